// Round 6
// baseline (441.586 us; speedup 1.0000x reference)
//
#include <hip/hip_runtime.h>
#include <cstdint>
#include <cstddef>

// x = x556 + x570 (fp32 [12544,1024]); LayerNorm over C=1024; y = xn @ W^T + b
// (W [4096,1024] fp32, row-major = B^T GEMM layout); out = gelu(y), fp32.
// Internal compute: bf16 MFMA 32x32x16; tanh-form GELU (|err| vs erf ~1e-3 << 6.4e-2 thr).
#define M_DIM 12544
#define K_DIM 1024
#define N_DIM 4096

typedef __bf16 bf16x8 __attribute__((ext_vector_type(8)));
typedef float f32x16 __attribute__((ext_vector_type(16)));

#define VMCNT(n)  asm volatile("s_waitcnt vmcnt(" #n ")" ::: "memory")
#define LGKM0()   asm volatile("s_waitcnt lgkmcnt(0)" ::: "memory")
#define SCHED0()  __builtin_amdgcn_sched_barrier(0)
#define BAR()     __builtin_amdgcn_s_barrier()

__device__ __forceinline__ unsigned short bf16_rne(float f) {
    unsigned int u = __float_as_uint(f);
    u += 0x7FFFu + ((u >> 16) & 1u);
    return (unsigned short)(u >> 16);
}
__device__ __forceinline__ unsigned int pack2_bf16(float lo, float hi) {
    return (unsigned int)bf16_rne(lo) | ((unsigned int)bf16_rne(hi) << 16);
}
// tanh-form GELU: x * sigmoid(1.5957691*x*(1+0.044715 x^2)); ~8 VALU ops vs erff's ~25.
__device__ __forceinline__ float gelu_fast(float x) {
    float t = 1.5957691216057308f * x * fmaf(0.044715f, x * x, 1.0f);
    float e = __expf(-t);                       // v_exp_f32
    return x * __builtin_amdgcn_rcpf(1.0f + e); // v_rcp_f32
}

// async global->LDS, 16B per lane. LDS dest must be wave-uniform base + lane*16.
__device__ __forceinline__ void async_load16(const void* g, void* l) {
    __builtin_amdgcn_global_load_lds(
        (const __attribute__((address_space(1))) void*)g,
        (__attribute__((address_space(3))) void*)l,
        16, 0, 0);
}

// -------- fused: residual add + LayerNorm -> bf16 xn  AND  W fp32 -> bf16 ----
// blocks [0,3136): LN rows (4 rows/block). blocks [3136,4160): W convert.
__global__ __launch_bounds__(256) void pre_fused(
    const float* __restrict__ x0,
    const float* __restrict__ x1,
    const float* __restrict__ gam,
    const float* __restrict__ bet,
    const float* __restrict__ Wlin,
    unsigned short* __restrict__ o,
    unsigned short* __restrict__ wb)
{
    const int bid = blockIdx.x;
    if (bid >= M_DIM / 4) {
        const int wbid = bid - M_DIM / 4;
        const float* wp = Wlin + (size_t)wbid * 4096;
        unsigned short* op = wb + (size_t)wbid * 4096;
        #pragma unroll
        for (int j = 0; j < 4; ++j) {
            float4 v = *(const float4*)(wp + j * 1024 + threadIdx.x * 4);
            uint2 r;
            r.x = pack2_bf16(v.x, v.y);
            r.y = pack2_bf16(v.z, v.w);
            *(uint2*)(op + j * 1024 + threadIdx.x * 4) = r;
        }
        return;
    }

    const int lane = threadIdx.x & 63;
    const int wv   = threadIdx.x >> 6;
    const size_t row = (size_t)bid * 4 + wv;
    const float* p0 = x0 + row * K_DIM;
    const float* p1 = x1 + row * K_DIM;

    float v[16];
    #pragma unroll
    for (int i = 0; i < 4; ++i) {
        float4 a = *(const float4*)(p0 + i * 256 + lane * 4);
        float4 b = *(const float4*)(p1 + i * 256 + lane * 4);
        v[4*i+0] = a.x + b.x; v[4*i+1] = a.y + b.y;
        v[4*i+2] = a.z + b.z; v[4*i+3] = a.w + b.w;
    }

    float s = 0.f, sq = 0.f;
    #pragma unroll
    for (int i = 0; i < 16; ++i) { s += v[i]; sq += v[i] * v[i]; }
    #pragma unroll
    for (int m = 32; m >= 1; m >>= 1) {
        s  += __shfl_xor(s,  m);
        sq += __shfl_xor(sq, m);
    }
    const float mean = s * (1.0f / 1024.0f);
    float var = sq * (1.0f / 1024.0f) - mean * mean;
    var = fmaxf(var, 0.0f);
    const float rstd = rsqrtf(var + 1e-5f);

    unsigned short* po = o + row * K_DIM;
    #pragma unroll
    for (int i = 0; i < 4; ++i) {
        float4 g  = *(const float4*)(gam + i * 256 + lane * 4);
        float4 be = *(const float4*)(bet + i * 256 + lane * 4);
        float y0 = (v[4*i+0] - mean) * rstd * g.x + be.x;
        float y1 = (v[4*i+1] - mean) * rstd * g.y + be.y;
        float y2 = (v[4*i+2] - mean) * rstd * g.z + be.z;
        float y3 = (v[4*i+3] - mean) * rstd * g.w + be.w;
        uint2 r;
        r.x = pack2_bf16(y0, y1);
        r.y = pack2_bf16(y2, y3);
        *(uint2*)(po + i * 256 + lane * 4) = r;
    }
}

// ---------------- GEMM: C[M,N] = gelu(A[M,K] @ B[N,K]^T + bias) ----------------
// 256x256 tile, 512 threads = 8 waves (2Mx4N), per-wave 128x64 via 4x2 of
// mfma_f32_32x32x16_bf16. LDS-read ratio 0.75 reads/mfma (the 128x128 tile's
// 1.0 ratio made the LDS pipe, not MFMA, the floor: 63us LDS vs 42us MFMA).
//
// HALF-K-TILE RING (m201-style depth): K split into 32 halves of 32 cols.
// 4-slot ring, each slot = A[256][32] + B[256][32] bf16 (32 KB); 128 KB total.
// Staging: 4 gload_lds per half (2 A-rounds + 2 B-rounds), issued 3 halves
// ahead (12 loads / 1.5 K-tiles in flight). Per half-step (2 phases, ks=0,1):
//   P0: 6 ds_reads (frags ks0) + stage A-rounds of half hh+3
//       BAR; lgkmcnt(0); sched_barrier; setprio(1); 8 MFMA; setprio(0); BAR
//   P1: same with ks1 + stage B-rounds; after MFMA: VMCNT(8) -- drains exactly
//       half hh+1 (issued 2 half-steps ago, ~600cy old), leaves 8 in flight --
//       then closing BAR doubles as the residency barrier for half hh+1.
// vmcnt never 0 in steady state (T4); tail peels 8->4->0.
//
// Swizzle: write phys seg (t&3) at row (t>>2); global lseg = ((t&3)-((t>>2)&3))&3;
// read pseg = (ks*2+h + (row&3))&3. Row stride 64B: 8 (parity x seg) classes x
// 4 lanes x 4 dwords = 8 dwords/bank = b128 floor.
__global__ __launch_bounds__(512, 2) void gemm_bias_gelu(
    const unsigned short* __restrict__ A,    // xn [M,K] bf16
    const unsigned short* __restrict__ B,    // W  [N,K] bf16
    const float* __restrict__ bias,          // [N] fp32
    float* __restrict__ C)                   // [M,N] fp32
{
    __shared__ __align__(16) unsigned short Ah[4][256 * 32];
    __shared__ __align__(16) unsigned short Bh[4][256 * 32];

    const int t  = threadIdx.x;          // 0..511
    const int bn = blockIdx.x;           // 0..15 fast-varying: XCD k sees 2 bn
    const int bm = blockIdx.y;           // 0..48  panels -> B L2-resident/XCD
    const int m0 = bm * 256, n0 = bn * 256;

    // staging: round r covers rows r*128; thread t -> row r*128+(t>>2),
    // phys seg t&3; global lseg = ((t&3) - ((t>>2)&3)) & 3
    const int srow = t >> 2;             // 0..127
    const int lseg = ((t & 3) - (srow & 3)) & 3;
    const unsigned short* agR0 = A + (size_t)(m0 + srow      ) * K_DIM + lseg * 8;
    const unsigned short* agR1 = A + (size_t)(m0 + srow + 128) * K_DIM + lseg * 8;
    const unsigned short* bgR0 = B + (size_t)(n0 + srow      ) * K_DIM + lseg * 8;
    const unsigned short* bgR1 = B + (size_t)(n0 + srow + 128) * K_DIM + lseg * 8;

    const int lane = t & 63;
    const int wid  = t >> 6;
    const int wr   = wid >> 2;           // 0..1: rows wr*128..+128
    const int wc   = wid & 3;            // 0..3: cols wc*64..+64
    const int ml   = lane & 31;
    const int h    = lane >> 5;

    f32x16 acc[4][2] = {};
    bf16x8 af[4], bf[2];

    auto stage2A = [&](int s) {          // A rounds of one half -> slot s
        async_load16(agR0, &Ah[s][       t * 8]);
        async_load16(agR1, &Ah[s][4096 + t * 8]);
        agR0 += 32; agR1 += 32;
    };
    auto stage2B = [&](int s) {          // B rounds of one half -> slot s
        async_load16(bgR0, &Bh[s][       t * 8]);
        async_load16(bgR1, &Bh[s][4096 + t * 8]);
        bgR0 += 32; bgR1 += 32;
    };

    // 6 fragment reads from slot s for k-slice ks (pseg = (ks*2+h+(ml&3))&3)
    auto dsr = [&](int s, int ks) {
        const int ps = ((ks * 2 + h) + (ml & 3)) & 3;
        #pragma unroll
        for (int i = 0; i < 4; ++i) {
            const int ra = wr * 128 + i * 32 + ml;
            af[i] = *(const bf16x8*)&Ah[s][ra * 32 + ps * 8];
        }
        #pragma unroll
        for (int j = 0; j < 2; ++j) {
            const int rb = wc * 64 + j * 32 + ml;
            bf[j] = *(const bf16x8*)&Bh[s][rb * 32 + ps * 8];
        }
    };
    auto mfma8 = [&]() {
        __builtin_amdgcn_s_setprio(1);
        #pragma unroll
        for (int i = 0; i < 4; ++i)
            #pragma unroll
            for (int j = 0; j < 2; ++j)
                acc[i][j] = __builtin_amdgcn_mfma_f32_32x32x16_bf16(
                    af[i], bf[j], acc[i][j], 0, 0, 0);
        __builtin_amdgcn_s_setprio(0);
    };

    // phase templates (closing vmcnt+BAR of P1 supplied by caller for tail ctl)
    auto p0 = [&](int s, int s3, bool stg) {
        dsr(s, 0);
        if (stg) stage2A(s3);
        SCHED0(); BAR(); LGKM0(); SCHED0();
        mfma8();
        SCHED0(); BAR();
    };
    auto p1 = [&](int s, int s3, bool stg) {
        dsr(s, 1);
        if (stg) stage2B(s3);
        SCHED0(); BAR(); LGKM0(); SCHED0();
        mfma8();
        SCHED0();
    };

    // prologue: halves 0,1,2 (FIFO: A0,B0,A1,B1,A2,B2 = 12 loads);
    // drain half 0 (leave 8), align.
    stage2A(0); stage2B(0);
    stage2A(1); stage2B(1);
    stage2A(2); stage2B(2);
    VMCNT(8); BAR();

    // half-steps hh=0..27 (7x4, slots cycle 0..3, stage hh+3)
    #pragma unroll 1
    for (int it = 0; it < 7; ++it) {
        p0(0, 3, true); p1(0, 3, true); VMCNT(8); BAR();
        p0(1, 0, true); p1(1, 0, true); VMCNT(8); BAR();
        p0(2, 1, true); p1(2, 1, true); VMCNT(8); BAR();
        p0(3, 2, true); p1(3, 2, true); VMCNT(8); BAR();
    }
    // hh=28: stages half 31 (last); drain half 29
    p0(0, 3, true);  p1(0, 3, true);  VMCNT(8); BAR();
    // hh=29..31: tail, no staging; drain 30, then 31, then done
    p0(1, 0, false); p1(1, 0, false); VMCNT(4); BAR();
    p0(2, 0, false); p1(2, 0, false); VMCNT(0); BAR();
    p0(3, 0, false); p1(3, 0, false);

    // epilogue: C/D layout col=ml (n), row=(reg&3)+8*(reg>>2)+4*h (m).
    // Nontemporal stores: the 205 MB C stream must not thrash A/B out of L3.
    #pragma unroll
    for (int j = 0; j < 2; ++j) {
        const int n = n0 + wc * 64 + j * 32 + ml;
        const float bj = bias[n];
        #pragma unroll
        for (int i = 0; i < 4; ++i) {
            const int mbase = m0 + wr * 128 + i * 32 + 4 * h;
            #pragma unroll
            for (int reg = 0; reg < 16; ++reg) {
                const int m = mbase + (reg & 3) + 8 * (reg >> 2);
                __builtin_nontemporal_store(gelu_fast(acc[i][j][reg] + bj),
                                            &C[(size_t)m * N_DIM + n]);
            }
        }
    }
}

extern "C" void kernel_launch(void* const* d_in, const int* in_sizes, int n_in,
                              void* d_out, int out_size, void* d_ws, size_t ws_size,
                              hipStream_t stream) {
    const float* x556 = (const float*)d_in[0];
    const float* x570 = (const float*)d_in[1];
    const float* gam  = (const float*)d_in[2];
    const float* bet  = (const float*)d_in[3];
    const float* Wlin = (const float*)d_in[4];
    const float* blin = (const float*)d_in[5];
    float* out = (float*)d_out;

    unsigned short* xn = (unsigned short*)d_ws;            // 25.69 MB
    unsigned short* wb = xn + (size_t)M_DIM * K_DIM;       // 8.39 MB

    pre_fused<<<M_DIM / 4 + 1024, 256, 0, stream>>>(x556, x570, gam, bet, Wlin, xn, wb);
    gemm_bias_gelu<<<dim3(N_DIM / 256, M_DIM / 256), 512, 0, stream>>>(xn, wb, blin, out);
}